// Round 3
// baseline (479.830 us; speedup 1.0000x reference)
//
#include <hip/hip_runtime.h>
#include <stdint.h>

typedef unsigned int u32;
typedef unsigned short u16;
typedef __attribute__((ext_vector_type(8))) short bf16x8;    // 8 bf16 = 4 VGPRs
typedef __attribute__((ext_vector_type(4))) float f32x4;     // 16x16 MFMA C/D
typedef __attribute__((ext_vector_type(16))) float f32x16;   // 32x32 MFMA C/D

#define B_ 4
#define S_ 4096
#define D_ 512
#define SCALE_ 0.04419417382415922f   // 512^-0.5

// ---------- helpers ----------
__device__ __forceinline__ u16 f2b(float f) {                // fp32 -> bf16 RNE (exact)
  u32 u = __builtin_bit_cast(u32, f);
  return (u16)((u + 0x7FFFu + ((u >> 16) & 1u)) >> 16);
}
__device__ __forceinline__ u16 f2b_fast(float f) {           // 2-op round
  u32 u = __builtin_bit_cast(u32, f);
  return (u16)((u + 0x8000u) >> 16);
}
__device__ __forceinline__ float b2f(u16 h) {
  u32 u = ((u32)h) << 16;
  return __builtin_bit_cast(float, u);
}
// async global->LDS, 16B/lane, dst = lds_base + lane*16 (wave-uniform base)
__device__ __forceinline__ void gld16(const void* g, void* l) {
  __builtin_amdgcn_global_load_lds(
      (const __attribute__((address_space(1))) u32*)g,
      (__attribute__((address_space(3))) u32*)l, 16, 0, 0);
}

// =====================================================================
// Kernel 0: Wb = bf16(W), one pass.
// =====================================================================
__global__ __launch_bounds__(256, 1) void qprep(
    const float* __restrict__ W, u16* __restrict__ Wb) {
  int i = (blockIdx.x * 256 + threadIdx.x) * 4;
  float4 a = *(const float4*)(W + i);
  ushort4 o;
  o.x = f2b(a.x); o.y = f2b(a.y); o.z = f2b(a.z); o.w = f2b(a.w);
  *(ushort4*)(Wb + i) = o;
}

// =====================================================================
// Kernel 1: Q = X @ W^T. 128x128 tiles, grid (128,4) = 2 blocks/CU.
// W tiles via double-buffered global_load_lds (2x16KB); X A-frags from
// global fp32 + in-reg cvt (no A-LDS). B-frags reused across 2 m-tiles.
// =====================================================================
__global__ __launch_bounds__(256, 2) void qproj(
    const float* __restrict__ X, const u16* __restrict__ Wb,
    u16* __restrict__ Qr, u16* __restrict__ Qt) {
  __shared__ __align__(16) u16 Wt[2][128 * 64];   // [n-row][k], mod-8 rotated blocks
  const int tid = threadIdx.x;
  const int wave = tid >> 6, lane = tid & 63;
  const int m16 = lane & 15, quad = lane >> 4;
  const int r0 = blockIdx.x * 128, n0 = blockIdx.y * 128;

  auto stageW = [&](int kc, int buf) {            // 16KB = 4 instr/wave, 8 rows each
#pragma unroll
    for (int t = 0; t < 4; ++t) {
      int p8 = (wave * 4 + t) * 8;
      int row = p8 + (lane >> 3);
      int gb = ((lane & 7) + row) & 7;            // pos p&7 holds global block ((p&7)+row)&7
      gld16(Wb + (size_t)(n0 + row) * D_ + kc * 64 + gb * 8, &Wt[buf][p8 * 64]);
    }
  };
  auto loadX = [&](int kc, float4* xr) {          // 4 frags (mt,kk) x 2 float4
#pragma unroll
    for (int mt = 0; mt < 2; ++mt)
#pragma unroll
      for (int kk = 0; kk < 2; ++kk) {
        const float* p = X + (size_t)(r0 + wave * 32 + mt * 16 + m16) * D_ +
                         kc * 64 + kk * 32 + quad * 8;
        xr[(mt * 2 + kk) * 2]     = ((const float4*)p)[0];
        xr[(mt * 2 + kk) * 2 + 1] = ((const float4*)p)[1];
      }
  };

  f32x4 acc[16];
#pragma unroll
  for (int i = 0; i < 16; ++i) acc[i] = f32x4{};
  float4 xr[8], xr2[8];

  loadX(0, xr);
  stageW(0, 0);
  __syncthreads();

  for (int kc = 0; kc < 8; ++kc) {
    if (kc < 7) { stageW(kc + 1, (kc + 1) & 1); loadX(kc + 1, xr2); }
    bf16x8 afr[4];
#pragma unroll
    for (int f = 0; f < 4; ++f) {
      float4 a0 = xr[f * 2], a1 = xr[f * 2 + 1];
      bf16x8 v;
      v[0] = (short)f2b(a0.x); v[1] = (short)f2b(a0.y);
      v[2] = (short)f2b(a0.z); v[3] = (short)f2b(a0.w);
      v[4] = (short)f2b(a1.x); v[5] = (short)f2b(a1.y);
      v[6] = (short)f2b(a1.z); v[7] = (short)f2b(a1.w);
      afr[f] = v;
    }
    const u16* wbase = &Wt[kc & 1][0];
#pragma unroll
    for (int nt = 0; nt < 8; ++nt) {
#pragma unroll
      for (int kk = 0; kk < 2; ++kk) {
        int ib = ((kk * 4 + quad) - m16) & 7;     // row&7 == m16&7
        bf16x8 bf = *(const bf16x8*)(wbase + (nt * 16 + m16) * 64 + ib * 8);
#pragma unroll
        for (int mt = 0; mt < 2; ++mt)
          acc[mt * 8 + nt] =
              __builtin_amdgcn_mfma_f32_16x16x32_bf16(afr[mt * 2 + kk], bf, acc[mt * 8 + nt], 0, 0, 0);
      }
    }
    if (kc < 7) {
#pragma unroll
      for (int i = 0; i < 8; ++i) xr[i] = xr2[i];
    }
    __syncthreads();
  }

  // epilogue: C rows = quad*4+r, cols = n0 + nt*16 + m16
#pragma unroll
  for (int mt = 0; mt < 2; ++mt) {
    const int grow = r0 + wave * 32 + mt * 16 + quad * 4;
    const int b = grow >> 12;
    const int s0 = grow & (S_ - 1);
#pragma unroll
    for (int nt = 0; nt < 8; ++nt) {
      int e = n0 + nt * 16 + m16;
      f32x4 a = acc[mt * 8 + nt];
      u16 h0 = f2b(a[0]), h1 = f2b(a[1]), h2 = f2b(a[2]), h3 = f2b(a[3]);
      Qr[(size_t)(grow + 0) * D_ + e] = h0;
      Qr[(size_t)(grow + 1) * D_ + e] = h1;
      Qr[(size_t)(grow + 2) * D_ + e] = h2;
      Qr[(size_t)(grow + 3) * D_ + e] = h3;
      uint2 pv;
      pv.x = (u32)h0 | ((u32)h1 << 16);
      pv.y = (u32)h2 | ((u32)h3 << 16);
      *(uint2*)(&Qt[((size_t)(b * D_ + e)) * S_ + s0]) = pv;
    }
  }
}

// =====================================================================
// Kernel 2: flash attention.
//  S-phase: S^T = K Q^T via 32x32x16 (waves = q-half x key-half); Q B-frags
//  resident in regs; softmax is in-lane (q = lane&31).
//  PV-phase: 16x16x32, shared swizzled P (XOR-block 64x64), waves split D
//  into 128-col slices -> V B-frags reused 4x.
// =====================================================================
__global__ __launch_bounds__(256, 1) void flashattn(
    const u16* __restrict__ Qrow, const u16* __restrict__ Qt,
    float* __restrict__ Out) {
  __shared__ __align__(16) u16 Kt[64 * 512];      // [key][d], mod-8 rotated
  __shared__ __align__(16) u16 Vt[512 * 64];      // [d][key], mod-8 rotated
  __shared__ __align__(16) u16 Psh[64 * 64];      // [q][key], XOR-block swizzle
  __shared__ float mxArr[2][2][32];               // [qg][kh][q]
  __shared__ float alphaArr[64];
  __shared__ float lsumArr[2][2][32];
  __shared__ int ldsFlag;

  const int tid = threadIdx.x;
  const int wave = tid >> 6, lane = tid & 63;
  const int m16 = lane & 15, quad = lane >> 4;
  const int l5 = lane & 31, half = lane >> 5;
  const int qg = wave >> 1, kh = wave & 1;
  const int qt = blockIdx.x, bb = blockIdx.y;
  const u16* Qb  = Qrow + (size_t)bb * S_ * D_;
  const u16* Qtb = Qt   + (size_t)bb * D_ * S_;

  auto stageK = [&](int kt) {
    const u16* src = Qb + (size_t)(kt * 64) * D_;
#pragma unroll
    for (int t = 0; t < 16; ++t) {
      int n = wave * 16 + t;
      int gb = (lane & ~7) | ((lane + n) & 7);
      gld16(src + (size_t)n * D_ + gb * 8, &Kt[n * 512]);
    }
  };
  auto stageV = [&](int kt) {
    const u16* vsrc = Qtb + kt * 64;
#pragma unroll
    for (int t = 0; t < 16; ++t) {
      int d0 = (wave * 16 + t) * 8;
      int d  = d0 + (lane >> 3);
      int gb = ((lane & 7) + d) & 7;
      gld16(vsrc + (size_t)d * S_ + gb * 8, &Vt[d0 * 64]);
    }
  };

  // Q B-frags (32x32x16): lane holds Q[qg*32+l5][s*16 + half*8 + j]
  bf16x8 qb[32];
  {
    const u16* qp = Qb + (size_t)(qt * 64 + qg * 32 + l5) * D_ + half * 8;
#pragma unroll
    for (int s = 0; s < 32; ++s) qb[s] = *(const bf16x8*)(qp + s * 16);
  }

  f32x4 o[32];                      // [mt][nt]: O[64 q][wave's 128-d slice]
#pragma unroll
  for (int i = 0; i < 32; ++i) o[i] = f32x4{};
  float mrow = -1e30f, lrow = 0.f;  // per-lane: q = qg*32 + l5 (this wave's key-half)

  stageK(0);
  __syncthreads();

  for (int kt = 0; kt < 64; ++kt) {
    // ===== phase A: V[kt] streams; S^T = K Q^T =====
    stageV(kt);
    if (tid == 0) ldsFlag = 0;

    f32x16 c0 = {}, c1 = {};
    const int n = kh * 32 + l5;                   // this lane's A-row (key)
    const u16* kr = &Kt[(size_t)n * 512];
#pragma unroll
    for (int s = 0; s < 32; s += 2) {
      int g0 = 2 * s + half, g1 = 2 * s + 2 + half;
      bf16x8 ka0 = *(const bf16x8*)(kr + ((g0 & ~7) | ((g0 - n) & 7)) * 8);
      bf16x8 ka1 = *(const bf16x8*)(kr + ((g1 & ~7) | ((g1 - n) & 7)) * 8);
      c0 = __builtin_amdgcn_mfma_f32_32x32x16_bf16(ka0, qb[s], c0, 0, 0, 0);
      c1 = __builtin_amdgcn_mfma_f32_32x32x16_bf16(ka1, qb[s + 1], c1, 0, 0, 0);
    }
    float sc[16];
#pragma unroll
    for (int i = 0; i < 16; ++i) sc[i] = c0[i] + c1[i];

    // in-lane max over 16 keys, + other 16 keys via lane^32
    float pmax = sc[0];
#pragma unroll
    for (int i = 1; i < 16; ++i) pmax = fmaxf(pmax, sc[i]);
    pmax = fmaxf(pmax, __shfl_xor(pmax, 32));
    if (lane < 32) mxArr[qg][kh][lane] = pmax;
    __syncthreads();                              // B1 (V mostly streamed by now)

    float mold = mrow;
    float mn = fmaxf(mold, fmaxf(mxArr[qg][0][l5], mxArr[qg][1][l5]));
    bool grew = mn > mold;
    float alpha = __expf((mold - mn) * SCALE_);
    mrow = mn;
    if (kh == 0 && lane < 32) alphaArr[qg * 32 + lane] = alpha;
    if (__ballot(grew) != 0ull && lane == 0) ldsFlag = 1;

    // exp, quantize, pack 4 keys -> b64 store into swizzled P; psum in-lane
    float psum = 0.f;
    const int q = qg * 32 + l5;
    u16* prow = &Psh[q * 64];
#pragma unroll
    for (int rr = 0; rr < 4; ++rr) {
      u16 h0 = f2b_fast(__expf((sc[rr * 4 + 0] - mn) * SCALE_));
      u16 h1 = f2b_fast(__expf((sc[rr * 4 + 1] - mn) * SCALE_));
      u16 h2 = f2b_fast(__expf((sc[rr * 4 + 2] - mn) * SCALE_));
      u16 h3 = f2b_fast(__expf((sc[rr * 4 + 3] - mn) * SCALE_));
      psum += b2f(h0) + b2f(h1) + b2f(h2) + b2f(h3);
      uint2 pk;
      pk.x = (u32)h0 | ((u32)h1 << 16);
      pk.y = (u32)h2 | ((u32)h3 << 16);
      int phys = (kh * 4 + rr) ^ (q & 7);
      *(uint2*)(prow + phys * 8 + half * 4) = pk;
    }
    psum += __shfl_xor(psum, 32);                 // all 32 of this wave's keys
    lrow = lrow * alpha + psum;

    __syncthreads();                              // B2: V drained, P + alpha visible

    // ===== phase B: K[kt+1] streams; O += P V =====
    if (kt < 63) stageK(kt + 1);

    int doRescale = ldsFlag;
    if (doRescale) {
      float al[16];
#pragma unroll
      for (int mt = 0; mt < 4; ++mt)
#pragma unroll
        for (int r = 0; r < 4; ++r) al[mt * 4 + r] = alphaArr[mt * 16 + quad * 4 + r];
#pragma unroll
      for (int mt = 0; mt < 4; ++mt)
#pragma unroll
        for (int nt = 0; nt < 8; ++nt) {
          o[mt * 8 + nt][0] *= al[mt * 4 + 0];
          o[mt * 8 + nt][1] *= al[mt * 4 + 1];
          o[mt * 8 + nt][2] *= al[mt * 4 + 2];
          o[mt * 8 + nt][3] *= al[mt * 4 + 3];
        }
    }

    bf16x8 pf[8];                                 // P A-frags [mt][ks2]
#pragma unroll
    for (int mt = 0; mt < 4; ++mt)
#pragma unroll
      for (int ks2 = 0; ks2 < 2; ++ks2) {
        int qr = mt * 16 + m16;
        int phys = (ks2 * 4 + quad) ^ (m16 & 7);
        pf[mt * 2 + ks2] = *(const bf16x8*)(&Psh[qr * 64 + phys * 8]);
      }
#pragma unroll
    for (int nt = 0; nt < 8; ++nt) {
      const u16* vrow = &Vt[(size_t)(wave * 128 + nt * 16 + m16) * 64];
#pragma unroll
      for (int ks2 = 0; ks2 < 2; ++ks2) {
        int ib = ((ks2 * 4 + quad) - m16) & 7;    // d&7 == m16&7
        bf16x8 vf = *(const bf16x8*)(vrow + ib * 8);
#pragma unroll
        for (int mt = 0; mt < 4; ++mt)
          o[mt * 8 + nt] =
              __builtin_amdgcn_mfma_f32_16x16x32_bf16(pf[mt * 2 + ks2], vf, o[mt * 8 + nt], 0, 0, 0);
      }
    }
    __syncthreads();                              // B3: K drained; Kt/Vt/P safe
  }

  // ---- epilogue ----
  if (lane < 32) lsumArr[qg][kh][lane] = lrow;
  __syncthreads();
  float linv[16];
#pragma unroll
  for (int mt = 0; mt < 4; ++mt)
#pragma unroll
    for (int r = 0; r < 4; ++r) {
      int qr = mt * 16 + quad * 4 + r;
      float l = lsumArr[qr >> 5][0][qr & 31] + lsumArr[qr >> 5][1][qr & 31];
      linv[mt * 4 + r] = 1.f / l;
    }
#pragma unroll
  for (int mt = 0; mt < 4; ++mt) {
    const int row0 = qt * 64 + mt * 16 + quad * 4;
#pragma unroll
    for (int nt = 0; nt < 8; ++nt) {
      int d = wave * 128 + nt * 16 + m16;
      size_t base = ((size_t)bb * S_ + row0) * D_ + d;
      Out[base]          = o[mt * 8 + nt][0] * linv[mt * 4 + 0];
      Out[base + D_]     = o[mt * 8 + nt][1] * linv[mt * 4 + 1];
      Out[base + 2 * D_] = o[mt * 8 + nt][2] * linv[mt * 4 + 2];
      Out[base + 3 * D_] = o[mt * 8 + nt][3] * linv[mt * 4 + 3];
    }
  }
}

// =====================================================================
extern "C" void kernel_launch(void* const* d_in, const int* in_sizes, int n_in,
                              void* d_out, int out_size, void* d_ws, size_t ws_size,
                              hipStream_t stream) {
  (void)in_sizes; (void)n_in; (void)out_size; (void)ws_size;
  const float* X = (const float*)d_in[0];
  const float* W = (const float*)d_in[1];
  float* Out = (float*)d_out;
  u16* Qr = (u16*)d_ws;                                   // [B*S][D] bf16
  u16* Qt = Qr + (size_t)B_ * S_ * D_;                    // [B][D][S] bf16
  u16* Wb = Qt + (size_t)B_ * D_ * S_;                    // [D][D]    bf16

  qprep<<<dim3(256), dim3(256), 0, stream>>>(W, Wb);
  qproj<<<dim3(128, 4), dim3(256), 0, stream>>>(X, Wb, Qr, Qt);
  flashattn<<<dim3(64, 4), dim3(256), 0, stream>>>(Qr, Qt, Out);
}

// Round 4
// 445.543 us; speedup vs baseline: 1.0770x; 1.0770x over previous
//
#include <hip/hip_runtime.h>
#include <stdint.h>

typedef unsigned int u32;
typedef unsigned short u16;
typedef __attribute__((ext_vector_type(8))) short bf16x8;    // 8 bf16 = 4 VGPRs
typedef __attribute__((ext_vector_type(4))) float f32x4;     // 16x16 MFMA C/D

#define B_ 4
#define S_ 4096
#define D_ 512
#define SCALE_ 0.04419417382415922f   // 512^-0.5
#define PSTR 72                       // P row stride in u16 (16B-aligned, bank-spread)

// ---------- helpers ----------
__device__ __forceinline__ u16 f2b(float f) {                // fp32 -> bf16 RNE (exact)
  u32 u = __builtin_bit_cast(u32, f);
  return (u16)((u + 0x7FFFu + ((u >> 16) & 1u)) >> 16);
}
__device__ __forceinline__ u16 f2b_fast(float f) {           // 2-op round
  u32 u = __builtin_bit_cast(u32, f);
  return (u16)((u + 0x8000u) >> 16);
}
__device__ __forceinline__ float b2f(u16 h) {
  u32 u = ((u32)h) << 16;
  return __builtin_bit_cast(float, u);
}
// async global->LDS, 16B/lane, dst = lds_base + lane*16 (wave-uniform base)
__device__ __forceinline__ void gld16(const void* g, void* l) {
  __builtin_amdgcn_global_load_lds(
      (const __attribute__((address_space(1))) u32*)g,
      (__attribute__((address_space(3))) u32*)l, 16, 0, 0);
}

// =====================================================================
// Kernel 0: Xb = bf16(X) and Wb = bf16(W), one pass.
// grid: 8192 blocks for X (8.4M elems) + 256 for W (262144).
// =====================================================================
__global__ __launch_bounds__(256, 2) void qprep(
    const float* __restrict__ X, const float* __restrict__ W,
    u16* __restrict__ Xb, u16* __restrict__ Wb) {
  int bid = blockIdx.x;
  const float* src;
  u16* dst;
  int i;
  if (bid < 8192) { src = X; dst = Xb; i = (bid * 256 + threadIdx.x) * 4; }
  else            { src = W; dst = Wb; i = ((bid - 8192) * 256 + threadIdx.x) * 4; }
  float4 a = *(const float4*)(src + i);
  ushort4 o;
  o.x = f2b(a.x); o.y = f2b(a.y); o.z = f2b(a.z); o.w = f2b(a.w);
  *(ushort4*)(dst + i) = o;
}

// =====================================================================
// Kernel 1: Q = Xb @ Wb^T (bf16 MFMA). 128x128 tiles, grid (128,4) =
// 512 blocks = 2/CU. W via double-buffered global_load_lds; X A-frags
// direct bf16 global loads (register double-buffer, no conversion).
// =====================================================================
__global__ __launch_bounds__(256, 2) void qproj(
    const u16* __restrict__ Xb, const u16* __restrict__ Wb,
    u16* __restrict__ Qr, u16* __restrict__ Qt) {
  __shared__ __align__(16) u16 Wt[2][128 * 64];   // [n-row][k], mod-8 rotated blocks
  const int tid = threadIdx.x;
  const int wave = tid >> 6, lane = tid & 63;
  const int m16 = lane & 15, quad = lane >> 4;
  const int r0 = blockIdx.x * 128, n0 = blockIdx.y * 128;

  auto stageW = [&](int kc, int buf) {            // 16KB = 4 instr/wave, 8 rows each
#pragma unroll
    for (int t = 0; t < 4; ++t) {
      int p8 = (wave * 4 + t) * 8;
      int row = p8 + (lane >> 3);
      int gb = ((lane & 7) + row) & 7;
      gld16(Wb + (size_t)(n0 + row) * D_ + kc * 64 + gb * 8, &Wt[buf][p8 * 64]);
    }
  };
  const u16* xrow = Xb + (size_t)(r0 + wave * 32 + m16) * D_ + quad * 8;
  auto loadA = [&](int kc, bf16x8* a) {           // frags (mt,kk)
#pragma unroll
    for (int mt = 0; mt < 2; ++mt)
#pragma unroll
      for (int kk = 0; kk < 2; ++kk)
        a[mt * 2 + kk] = *(const bf16x8*)(xrow + (size_t)(mt * 16) * D_ + kc * 64 + kk * 32);
  };

  f32x4 acc[16];
#pragma unroll
  for (int i = 0; i < 16; ++i) acc[i] = f32x4{};
  bf16x8 afA[4], afB[4];

  loadA(0, afA);
  stageW(0, 0);
  __syncthreads();

  for (int kc = 0; kc < 8; ++kc) {
    if (kc < 7) { stageW(kc + 1, (kc + 1) & 1); loadA(kc + 1, afB); }
    const u16* wbase = &Wt[kc & 1][0];
#pragma unroll
    for (int nt = 0; nt < 8; ++nt) {
#pragma unroll
      for (int kk = 0; kk < 2; ++kk) {
        int ib = ((kk * 4 + quad) - m16) & 7;     // row&7 == m16&7
        bf16x8 bf = *(const bf16x8*)(wbase + (nt * 16 + m16) * 64 + ib * 8);
#pragma unroll
        for (int mt = 0; mt < 2; ++mt)
          acc[mt * 8 + nt] =
              __builtin_amdgcn_mfma_f32_16x16x32_bf16(afA[mt * 2 + kk], bf, acc[mt * 8 + nt], 0, 0, 0);
      }
    }
    if (kc < 7) {
#pragma unroll
      for (int i = 0; i < 4; ++i) afA[i] = afB[i];
    }
    __syncthreads();
  }

  // epilogue: C rows = quad*4+r, cols = n0 + nt*16 + m16
#pragma unroll
  for (int mt = 0; mt < 2; ++mt) {
    const int grow = r0 + wave * 32 + mt * 16 + quad * 4;
    const int b = grow >> 12;
    const int s0 = grow & (S_ - 1);
#pragma unroll
    for (int nt = 0; nt < 8; ++nt) {
      int e = n0 + nt * 16 + m16;
      f32x4 a = acc[mt * 8 + nt];
      u16 h0 = f2b(a[0]), h1 = f2b(a[1]), h2 = f2b(a[2]), h3 = f2b(a[3]);
      Qr[(size_t)(grow + 0) * D_ + e] = h0;
      Qr[(size_t)(grow + 1) * D_ + e] = h1;
      Qr[(size_t)(grow + 2) * D_ + e] = h2;
      Qr[(size_t)(grow + 3) * D_ + e] = h3;
      uint2 pv;
      pv.x = (u32)h0 | ((u32)h1 << 16);
      pv.y = (u32)h2 | ((u32)h3 << 16);
      *(uint2*)(&Qt[((size_t)(b * D_ + e)) * S_ + s0]) = pv;
    }
  }
}

// =====================================================================
// Kernel 2: flash attention, 512 threads (8 waves = 2/SIMD), Qm=64,
// Bc=64, grid (64,4)=256 blocks, 1 block/CU.
//  S-phase:  wave (qh=w>>1, kh=w&1) -> S[16q x 32k]; Q frags in regs;
//            K B-frags from LDS Kt (DMA-staged, mod-8 rotated).
//  softmax:  partial max -> LDS -> B1 -> alpha/exp/P(LDS) -> B2.
//  PV-phase: wave (qhp=w&1, dh=w>>1) -> O[32q x 128d]; V B-frags read
//            DIRECT from global Qt (L1/L2-served); P A-frags from LDS.
//  K[kt+1] DMA issued after B2, drains at B3 under the PV phase.
// =====================================================================
__global__ __launch_bounds__(512, 2) void flashattn(
    const u16* __restrict__ Qrow, const u16* __restrict__ Qt,
    float* __restrict__ Out) {
  __shared__ __align__(16) u16 Kt[64 * 512];      // 64KB [key][d], mod-8 rotated
  __shared__ __align__(16) u16 Psh[64 * PSTR];    // 9KB  [q][key], stride 72
  __shared__ float mxArr[4][2][16];               // [qh][kh][q16] partial maxes
  __shared__ float alphaArr[64];
  __shared__ float lsumArr[2][64];                // [kh][q]
  __shared__ int ldsFlag;

  const int tid = threadIdx.x;
  const int wave = tid >> 6, lane = tid & 63;
  const int m16 = lane & 15, quad = lane >> 4;
  const int qh = wave >> 1, kh = wave & 1;        // S-phase role
  const int qhp = wave & 1, dh = wave >> 1;       // PV-phase role
  const int qt = blockIdx.x, bb = blockIdx.y;
  const u16* Qb  = Qrow + (size_t)bb * S_ * D_;
  const u16* Qtb = Qt   + (size_t)bb * D_ * S_;

  auto stageK = [&](int kt) {                     // 64 rows, 8 gld16/wave
    const u16* src = Qb + (size_t)(kt * 64) * D_;
#pragma unroll
    for (int t = 0; t < 8; ++t) {
      int n = wave * 8 + t;
      int gb = (lane & ~7) | ((lane + n) & 7);
      gld16(src + (size_t)n * D_ + gb * 8, &Kt[n * 512]);
    }
  };

  // Q A-frags for this wave's 16 q-rows (S-phase): 64 VGPR
  bf16x8 qf[16];
  {
    const u16* qp = Qb + (size_t)(qt * 64 + qh * 16 + m16) * D_ + quad * 8;
#pragma unroll
    for (int ks = 0; ks < 16; ++ks) qf[ks] = *(const bf16x8*)(qp + ks * 32);
  }

  f32x4 o[16];                                    // O[32q x 128d]: [mt][nt]
#pragma unroll
  for (int i = 0; i < 16; ++i) o[i] = f32x4{};
  float mrow[4] = {-1e30f, -1e30f, -1e30f, -1e30f};
  float lrow[4] = {0.f, 0.f, 0.f, 0.f};

  // V-frag global base for PV role: d = dh*128 + nt*16 + m16, key chunk quad*8
  const u16* vbase = Qtb + (size_t)(dh * 128 + m16) * S_ + quad * 8;

  stageK(0);
  __syncthreads();

  for (int kt = 0; kt < 64; ++kt) {
    if (tid == 0) ldsFlag = 0;
    // ---- issue V-frag loads, half ks2=0 (drain free at B1) ----
    bf16x8 vf0[8], vf1[8];
    const u16* vkt = vbase + kt * 64;
#pragma unroll
    for (int nt = 0; nt < 8; ++nt)
      vf0[nt] = *(const bf16x8*)(vkt + (size_t)(nt * 16) * S_);

    // ---- S = Q K^T for this wave's [16q x 32k] ----
    f32x4 sv[2];
#pragma unroll
    for (int nt = 0; nt < 2; ++nt) {
      f32x4 a = f32x4{};
      const int n = kh * 32 + nt * 16 + m16;
      const u16* kr = &Kt[(size_t)n * 512];
#pragma unroll
      for (int ks = 0; ks < 16; ++ks) {
        int jb = 4 * ks + quad;
        int ib = (jb & ~7) | ((jb - n) & 7);
        bf16x8 bf = *(const bf16x8*)(kr + ib * 8);
        a = __builtin_amdgcn_mfma_f32_16x16x32_bf16(qf[ks], bf, a, 0, 0, 0);
      }
      sv[nt] = a;
    }

    // ---- partial row max over this wave's 32 keys ----
    float pm[4];
#pragma unroll
    for (int r = 0; r < 4; ++r) {
      float t = fmaxf(sv[0][r], sv[1][r]);
      t = fmaxf(t, __shfl_xor(t, 1));
      t = fmaxf(t, __shfl_xor(t, 2));
      t = fmaxf(t, __shfl_xor(t, 4));
      t = fmaxf(t, __shfl_xor(t, 8));
      pm[r] = t;
    }
    if (m16 == 0) {
      mxArr[qh][kh][quad * 4 + 0] = pm[0];
      mxArr[qh][kh][quad * 4 + 1] = pm[1];
      mxArr[qh][kh][quad * 4 + 2] = pm[2];
      mxArr[qh][kh][quad * 4 + 3] = pm[3];
    }
    __syncthreads();                              // B1: maxes visible, V0 drained

    // ---- issue second half of V frags (drain at B2) ----
#pragma unroll
    for (int nt = 0; nt < 8; ++nt)
      vf1[nt] = *(const bf16x8*)(vkt + (size_t)(nt * 16) * S_ + 32);

    float alpha[4], mn[4];
    int grew = 0;
#pragma unroll
    for (int r = 0; r < 4; ++r) {
      float t = fmaxf(mxArr[qh][0][quad * 4 + r], mxArr[qh][1][quad * 4 + r]);
      float m2 = fmaxf(mrow[r], t);
      mn[r] = m2;
      grew |= (m2 > mrow[r]);
      alpha[r] = __expf((mrow[r] - m2) * SCALE_);
      mrow[r] = m2;
    }
    if (kh == 0 && m16 == 0) {
      alphaArr[qh * 16 + quad * 4 + 0] = alpha[0];
      alphaArr[qh * 16 + quad * 4 + 1] = alpha[1];
      alphaArr[qh * 16 + quad * 4 + 2] = alpha[2];
      alphaArr[qh * 16 + quad * 4 + 3] = alpha[3];
    }
    if (__ballot(grew) != 0ull && lane == 0) ldsFlag = 1;

    // ---- exp, quantize, write P; quantized psum for l ----
#pragma unroll
    for (int r = 0; r < 4; ++r) {
      const int q = qh * 16 + quad * 4 + r;
      u16 h0 = f2b_fast(__expf((sv[0][r] - mn[r]) * SCALE_));
      u16 h1 = f2b_fast(__expf((sv[1][r] - mn[r]) * SCALE_));
      Psh[q * PSTR + kh * 32 + m16]      = h0;
      Psh[q * PSTR + kh * 32 + 16 + m16] = h1;
      float ps = b2f(h0) + b2f(h1);
      ps += __shfl_xor(ps, 1);
      ps += __shfl_xor(ps, 2);
      ps += __shfl_xor(ps, 4);
      ps += __shfl_xor(ps, 8);
      lrow[r] = lrow[r] * alpha[r] + ps;
    }
    __syncthreads();                              // B2: P + alpha visible, V1 drained

    // ---- K[kt+1] DMA flies under the whole PV phase ----
    if (kt < 63) stageK(kt + 1);

    if (ldsFlag) {
      float al[8];
#pragma unroll
      for (int mt = 0; mt < 2; ++mt)
#pragma unroll
        for (int r = 0; r < 4; ++r)
          al[mt * 4 + r] = alphaArr[qhp * 32 + mt * 16 + quad * 4 + r];
#pragma unroll
      for (int mt = 0; mt < 2; ++mt)
#pragma unroll
        for (int nt = 0; nt < 8; ++nt) {
          o[mt * 8 + nt][0] *= al[mt * 4 + 0];
          o[mt * 8 + nt][1] *= al[mt * 4 + 1];
          o[mt * 8 + nt][2] *= al[mt * 4 + 2];
          o[mt * 8 + nt][3] *= al[mt * 4 + 3];
        }
    }

    // ---- O += P V : P A-frags from LDS, V B-frags from regs ----
    bf16x8 pf[4];                                 // [mt][ks2]
#pragma unroll
    for (int mt = 0; mt < 2; ++mt)
#pragma unroll
      for (int ks2 = 0; ks2 < 2; ++ks2)
        pf[mt * 2 + ks2] = *(const bf16x8*)(
            &Psh[(qhp * 32 + mt * 16 + m16) * PSTR + ks2 * 32 + quad * 8]);
#pragma unroll
    for (int nt = 0; nt < 8; ++nt) {
#pragma unroll
      for (int mt = 0; mt < 2; ++mt) {
        o[mt * 8 + nt] =
            __builtin_amdgcn_mfma_f32_16x16x32_bf16(pf[mt * 2], vf0[nt], o[mt * 8 + nt], 0, 0, 0);
        o[mt * 8 + nt] =
            __builtin_amdgcn_mfma_f32_16x16x32_bf16(pf[mt * 2 + 1], vf1[nt], o[mt * 8 + nt], 0, 0, 0);
      }
    }
    __syncthreads();                              // B3: P reads done, K DMA drained
  }

  // ---- epilogue: combine l halves, y = O / l ----
  if (m16 == 0) {
    lsumArr[kh][qh * 16 + quad * 4 + 0] = lrow[0];
    lsumArr[kh][qh * 16 + quad * 4 + 1] = lrow[1];
    lsumArr[kh][qh * 16 + quad * 4 + 2] = lrow[2];
    lsumArr[kh][qh * 16 + quad * 4 + 3] = lrow[3];
  }
  __syncthreads();
  float linv[8];
#pragma unroll
  for (int mt = 0; mt < 2; ++mt)
#pragma unroll
    for (int r = 0; r < 4; ++r) {
      int q = qhp * 32 + mt * 16 + quad * 4 + r;
      linv[mt * 4 + r] = 1.f / (lsumArr[0][q] + lsumArr[1][q]);
    }
#pragma unroll
  for (int mt = 0; mt < 2; ++mt) {
    const int row0 = qt * 64 + qhp * 32 + mt * 16 + quad * 4;
#pragma unroll
    for (int nt = 0; nt < 8; ++nt) {
      int d = dh * 128 + nt * 16 + m16;
      size_t base = ((size_t)bb * S_ + row0) * D_ + d;
      Out[base]          = o[mt * 8 + nt][0] * linv[mt * 4 + 0];
      Out[base + D_]     = o[mt * 8 + nt][1] * linv[mt * 4 + 1];
      Out[base + 2 * D_] = o[mt * 8 + nt][2] * linv[mt * 4 + 2];
      Out[base + 3 * D_] = o[mt * 8 + nt][3] * linv[mt * 4 + 3];
    }
  }
}

// =====================================================================
extern "C" void kernel_launch(void* const* d_in, const int* in_sizes, int n_in,
                              void* d_out, int out_size, void* d_ws, size_t ws_size,
                              hipStream_t stream) {
  (void)in_sizes; (void)n_in; (void)out_size; (void)ws_size;
  const float* X = (const float*)d_in[0];
  const float* W = (const float*)d_in[1];
  float* Out = (float*)d_out;
  u16* Qr = (u16*)d_ws;                                   // [B*S][D] bf16 16.8MB
  u16* Qt = Qr + (size_t)B_ * S_ * D_;                    // [B][D][S] bf16 16.8MB
  u16* Xb = Qt + (size_t)B_ * D_ * S_;                    // [B*S][D]  bf16 16.8MB
  u16* Wb = Xb + (size_t)B_ * S_ * D_;                    // [D][D]    bf16 0.5MB

  qprep<<<dim3(8448), dim3(256), 0, stream>>>(X, W, Xb, Wb);
  qproj<<<dim3(128, 4), dim3(256), 0, stream>>>(Xb, Wb, Qr, Qt);
  flashattn<<<dim3(64, 4), dim3(512), 0, stream>>>(Qr, Qt, Out);
}